// Round 1
// 240.253 us; speedup vs baseline: 1.0972x; 1.0972x over previous
//
#include <hip/hip_runtime.h>
#include <stdint.h>

#define F0    2048      // base input features (= GEMM K)
#define EROWS 512       // embed rows per level
#define NOUT  2048      // output features (= GEMM N)
#define MROWS 8192      // batch (= GEMM M)

typedef __attribute__((ext_vector_type(8))) short bf16x8;
typedef __attribute__((ext_vector_type(4))) float f32x4;
typedef __attribute__((ext_vector_type(8))) unsigned short u16x8;

typedef const __attribute__((address_space(1))) unsigned char ga_t;
typedef __attribute__((address_space(3))) unsigned char lds_t;

__device__ __forceinline__ void async_load16(const void* g, void* l) {
  __builtin_amdgcn_global_load_lds((ga_t*)g, (lds_t*)l, 16, 0, 0);
}

__device__ __forceinline__ unsigned short f2bf(float f) {
  unsigned int u = __builtin_bit_cast(unsigned int, f);
  u += 0x7fffu + ((u >> 16) & 1u);   // round-to-nearest-even
  return (unsigned short)(u >> 16);
}

// ---------------------------------------------------------------------------
// Blocks 0..3: CSR-ize weight b. Latency-optimized: 8 contiguous entries per
// thread per round (int4 x2 loads), parallel scan (no thread0 serial loop).
// Blocks 4..2051: x -> bf16 cast (1024 vec8 per block).
// ---------------------------------------------------------------------------
__global__ __launch_bounds__(256) void csr_cast_kernel(
    const int* __restrict__ r0, const int* __restrict__ c0, const float* __restrict__ v0, int n0,
    const int* __restrict__ r1, const int* __restrict__ c1, const float* __restrict__ v1, int n1,
    const int* __restrict__ r2, const int* __restrict__ c2, const float* __restrict__ v2, int n2,
    const int* __restrict__ rm, const int* __restrict__ cm, const float* __restrict__ vm, int nm,
    int* __restrict__ rp_all, int* __restrict__ cc_all, float* __restrict__ cv_all,
    const float* __restrict__ x, unsigned short* __restrict__ Ab)
{
  const int b = blockIdx.x;
  const int tid = threadIdx.x;

  if (b >= 4) {
    // ---- x cast: 16,777,216 floats = 2,097,152 vec8; 2048 blocks x 1024 vec8
    const int cb = b - 4;
    const float4* xp = (const float4*)x;
    u16x8* ap = (u16x8*)Ab;
#pragma unroll
    for (int it = 0; it < 4; ++it) {
      int i = cb * 1024 + it * 256 + tid;
      float4 a = xp[2 * i], c = xp[2 * i + 1];
      u16x8 o;
      o[0] = f2bf(a.x); o[1] = f2bf(a.y); o[2] = f2bf(a.z); o[3] = f2bf(a.w);
      o[4] = f2bf(c.x); o[5] = f2bf(c.y); o[6] = f2bf(c.z); o[7] = f2bf(c.w);
      ap[i] = o;
    }
    return;
  }

  // ---- CSR-ize one weight
  const int* rows; const int* cols; const float* vals; int nnz, nrows;
  if      (b == 0) { rows = r0; cols = c0; vals = v0; nnz = n0; nrows = EROWS; }
  else if (b == 1) { rows = r1; cols = c1; vals = v1; nnz = n1; nrows = EROWS; }
  else if (b == 2) { rows = r2; cols = c2; vals = v2; nnz = n2; nrows = EROWS; }
  else             { rows = rm; cols = cm; vals = vm; nnz = nm; nrows = NOUT; }
  int* rp  = rp_all + b * 4096;
  int* cc  = cc_all + b * 8192;          // main (b=3) spills into 16384 entries: region sized for it
  float* cv = cv_all + b * 8192;

  __shared__ int hist[NOUT + 1];
  __shared__ int tsum[256];

  for (int i = tid; i < nrows; i += 256) hist[i] = 0;
  __syncthreads();

  // --- histogram: 8 contiguous entries per thread per round
  int k0 = 0;
  for (; k0 + 2048 <= nnz; k0 += 2048) {
    const int kk = k0 + tid * 8;
    int4 ra = *(const int4*)(rows + kk);
    int4 rb = *(const int4*)(rows + kk + 4);
    atomicAdd(&hist[ra.x], 1); atomicAdd(&hist[ra.y], 1);
    atomicAdd(&hist[ra.z], 1); atomicAdd(&hist[ra.w], 1);
    atomicAdd(&hist[rb.x], 1); atomicAdd(&hist[rb.y], 1);
    atomicAdd(&hist[rb.z], 1); atomicAdd(&hist[rb.w], 1);
  }
  for (int k = k0 + tid; k < nnz; k += 256) atomicAdd(&hist[rows[k]], 1);
  __syncthreads();

  // --- exclusive scan: per-thread partials + parallel Hillis-Steele on 256
  const int per = nrows >> 8;            // 2 or 8
  const int base = tid * per;
  int sum = 0;
  for (int i = 0; i < per; ++i) sum += hist[base + i];
  tsum[tid] = sum;
  __syncthreads();
  for (int off = 1; off < 256; off <<= 1) {
    int add = (tid >= off) ? tsum[tid - off] : 0;
    __syncthreads();
    tsum[tid] += add;
    __syncthreads();
  }
  int run = (tid == 0) ? 0 : tsum[tid - 1];
  for (int i = 0; i < per; ++i) { int h = hist[base + i]; hist[base + i] = run; run += h; }
  __syncthreads();

  for (int i = tid; i < nrows; i += 256) rp[i] = hist[i];
  if (tid == 0) rp[nrows] = nnz;
  __syncthreads();

  // --- scatter: 8 contiguous entries per thread per round (hist = cursors)
  k0 = 0;
  for (; k0 + 2048 <= nnz; k0 += 2048) {
    const int kk = k0 + tid * 8;
    int4   ra = *(const int4*)(rows + kk);
    int4   rb = *(const int4*)(rows + kk + 4);
    int4   ca = *(const int4*)(cols + kk);
    int4   cb2 = *(const int4*)(cols + kk + 4);
    float4 va = *(const float4*)(vals + kk);
    float4 vb = *(const float4*)(vals + kk + 4);
    int p;
    p = atomicAdd(&hist[ra.x], 1); cc[p] = ca.x;  cv[p] = va.x;
    p = atomicAdd(&hist[ra.y], 1); cc[p] = ca.y;  cv[p] = va.y;
    p = atomicAdd(&hist[ra.z], 1); cc[p] = ca.z;  cv[p] = va.z;
    p = atomicAdd(&hist[ra.w], 1); cc[p] = ca.w;  cv[p] = va.w;
    p = atomicAdd(&hist[rb.x], 1); cc[p] = cb2.x; cv[p] = vb.x;
    p = atomicAdd(&hist[rb.y], 1); cc[p] = cb2.y; cv[p] = vb.y;
    p = atomicAdd(&hist[rb.z], 1); cc[p] = cb2.z; cv[p] = vb.z;
    p = atomicAdd(&hist[rb.w], 1); cc[p] = cb2.w; cv[p] = vb.w;
  }
  for (int k = k0 + tid; k < nnz; k += 256) {
    int p = atomicAdd(&hist[rows[k]], 1);
    cc[p] = cols[k]; cv[p] = vals[k];
  }
}

// ---------------------------------------------------------------------------
// One block per dense output row. Direct entries (c<F0) -> LDS atomics;
// indirect (c>=F0) -> register AXPY with prior dense row Dsrc[c-F0].
// Each thread owns 8 consecutive columns. BF16OUT writes u16x8 directly.
// ---------------------------------------------------------------------------
template <bool BF16OUT>
__global__ __launch_bounds__(256) void expand_csr_kernel(
    const int* __restrict__ rp, const int* __restrict__ cc,
    const float* __restrict__ cv, const float* __restrict__ Dsrc,
    void* __restrict__ out)
{
  const int r = blockIdx.x;
  const int tid = threadIdx.x;
  __shared__ float acc[F0];
  __shared__ int   icol[128];
  __shared__ float ival[128];
  __shared__ int   icnt;

  float4* a4 = (float4*)acc;
  a4[tid * 2]     = (float4){0.f, 0.f, 0.f, 0.f};
  a4[tid * 2 + 1] = (float4){0.f, 0.f, 0.f, 0.f};
  if (tid == 0) icnt = 0;
  __syncthreads();

  const int s = rp[r], e = rp[r + 1];
  for (int i = s + tid; i < e; i += 256) {
    int c = cc[i]; float v = cv[i];
    if (c < F0) atomicAdd(&acc[c], v);
    else { int p = atomicAdd(&icnt, 1); if (p < 128) { icol[p] = c - F0; ival[p] = v; } }
  }
  __syncthreads();
  int n = icnt; if (n > 128) n = 128;

  float4 q0 = a4[tid * 2], q1 = a4[tid * 2 + 1];
  for (int j = 0; j < n; ++j) {
    const float4* src = (const float4*)(Dsrc + (size_t)icol[j] * F0) + tid * 2;
    float v = ival[j];
    float4 s0 = src[0], s1 = src[1];
    q0.x += v * s0.x; q0.y += v * s0.y; q0.z += v * s0.z; q0.w += v * s0.w;
    q1.x += v * s1.x; q1.y += v * s1.y; q1.z += v * s1.z; q1.w += v * s1.w;
  }

  if (BF16OUT) {
    u16x8 o;
    o[0] = f2bf(q0.x); o[1] = f2bf(q0.y); o[2] = f2bf(q0.z); o[3] = f2bf(q0.w);
    o[4] = f2bf(q1.x); o[5] = f2bf(q1.y); o[6] = f2bf(q1.z); o[7] = f2bf(q1.w);
    ((u16x8*)out)[(size_t)r * 256 + tid] = o;
  } else {
    float4* dst = (float4*)out + (size_t)r * 512 + tid * 2;
    dst[0] = q0; dst[1] = q1;
  }
}

// ---------------------------------------------------------------------------
// C[m,n] = sum_k A[m,k] * B[n,k]   (A: MROWSxK bf16, B: NOUTxK bf16, C fp32)
// 256x256 tile, BK=64, 512 threads = 8 waves (2M x 4N), per-wave 128x64 out.
// 8-phase schedule (4 phases per K-tile, 2 K-tiles per LDS residency):
//   P1: ds-read A[q0](8)+B0(4) | stage A1(t+1) | bar | lgkm0 | 16 MFMA | bar
//   P2: ds-read B1(4)          |               | bar | lgkm0 | 16 MFMA | bar
//   P3: ds-read A[q1](8)       | stage B0(t+2) | bar | lgkm0 | 16 MFMA | bar
//   P4:                        | stage B1,A0(t+2) | bar |    | 16 MFMA | vmcnt(6) | bar
// Counted vmcnt: 3 half-tiles (6 global_load_lds instrs) stay in flight across
// barriers; never drained to 0 in the main loop (T3+T4). setprio around MFMA
// clusters (T5). XOR-swizzled LDS (group ^ row&7), pre-swizzled global source
// + linear global_load_lds dest (both-sides involution). 128 KiB dynamic LDS.
// Region-free proof: B-halves of tile t last read in P2 (both qn phases touch
// both halves via wc rows) -> staged at P3/P4 after P2's closing barrier;
// A-halves last read in P3 -> staged at P4 / next tile's P1.
// ---------------------------------------------------------------------------
__global__ __launch_bounds__(512, 2) void gemm256_kernel(
    const unsigned short* __restrict__ A, const unsigned short* __restrict__ B,
    float* __restrict__ C)
{
  constexpr int K  = F0;        // 2048
  constexpr int N  = NOUT;      // 2048
  constexpr int NT = K / 64;    // 32 K-tiles

  extern __shared__ __align__(16) unsigned short lds[];
  unsigned short* sA = lds;           // [2 buf][256 rows][64] bf16 = 64 KiB
  unsigned short* sB = lds + 32768;   // [2 buf][256 rows][64] bf16 = 64 KiB

  const int tid  = threadIdx.x;
  const int lane = tid & 63;
  const int w    = tid >> 6;          // 0..7
  const int wr   = w >> 2;            // 0..1  (M half of the block tile)
  const int wc   = w & 3;             // 0..3  (N quarter)
  const int mm   = lane & 15;
  const int g    = lane >> 4;         // 0..3
  const int sx   = mm & 7;            // per-thread swizzle xor
  const int bm   = blockIdx.y;
  const int bn   = blockIdx.x;

  const unsigned short* Ag = A + (size_t)bm * 256 * K;
  const unsigned short* Bg = B + (size_t)bn * 256 * K;

  // --- staging addressing: thread covers u0=tid (row r0, swz group c0) and
  // u1=512+tid (row 64+r0, same c0 since (64+r0)&7 == r0&7). LDS dest linear.
  const int    r0    = tid >> 3;
  const int    c0    = (tid & 7) ^ (r0 & 7);
  const size_t goff0 = (size_t)r0 * K + c0 * 8;            // elems
  const size_t goff1 = goff0 + (size_t)64 * K;
  const int    loff0 = tid * 8;                            // elems in half region
  const int    loff1 = 4096 + tid * 8;

#define STG(Gb, Sb, buf, h, t) do {                                           \
    async_load16((Gb) + goff0 + (size_t)(h) * 128 * K + (t) * 64,             \
                 (Sb) + (buf) * 16384 + (h) * 8192 + loff0);                  \
    async_load16((Gb) + goff1 + (size_t)(h) * 128 * K + (t) * 64,             \
                 (Sb) + (buf) * 16384 + (h) * 8192 + loff1);                  \
  } while (0)

  // --- fragment read bases (swizzled slots; row&7 == mm&7 for all frag rows)
  const unsigned short* paB = sA + (wr * 128 + mm) * 64;
  const unsigned short* pbB = sB + (wc * 64  + mm) * 64;
  const int s0 = ((0 * 4 + g) ^ sx) * 8;   // ks=0 slot offset (elems)
  const int s1 = ((1 * 4 + g) ^ sx) * 8;   // ks=1

  bf16x8 af[4][2];      // current A quadrant (qm): 4 m-reps x 2 ksteps
  bf16x8 bf0[2][2];     // B qn=0: 2 n-reps x 2 ksteps (lives P1..P4)
  bf16x8 bf1[2][2];     // B qn=1 (lives P2..P3)

#define LDA(buf, qm) do {                                                     \
    const unsigned short* p_ = paB + (buf) * 16384 + (qm) * 4096;             \
    _Pragma("unroll") for (int tm = 0; tm < 4; ++tm) {                        \
      af[tm][0] = *(const bf16x8*)(p_ + tm * 1024 + s0);                      \
      af[tm][1] = *(const bf16x8*)(p_ + tm * 1024 + s1);                      \
    } } while (0)

#define LDB(dst, buf, qn) do {                                                \
    const unsigned short* p_ = pbB + (buf) * 16384 + (qn) * 2048;             \
    _Pragma("unroll") for (int tn = 0; tn < 2; ++tn) {                        \
      dst[tn][0] = *(const bf16x8*)(p_ + tn * 1024 + s0);                     \
      dst[tn][1] = *(const bf16x8*)(p_ + tn * 1024 + s1);                     \
    } } while (0)

#define PH_MFMA(qm, qn, bfX) do {                                             \
    __builtin_amdgcn_s_setprio(1);                                            \
    _Pragma("unroll") for (int tm = 0; tm < 4; ++tm)                          \
    _Pragma("unroll") for (int tn = 0; tn < 2; ++tn) {                        \
      acc[(qm)*4+tm][(qn)*2+tn] = __builtin_amdgcn_mfma_f32_16x16x32_bf16(    \
          af[tm][0], bfX[tn][0], acc[(qm)*4+tm][(qn)*2+tn], 0, 0, 0);         \
      acc[(qm)*4+tm][(qn)*2+tn] = __builtin_amdgcn_mfma_f32_16x16x32_bf16(    \
          af[tm][1], bfX[tn][1], acc[(qm)*4+tm][(qn)*2+tn], 0, 0, 0);         \
    }                                                                         \
    __builtin_amdgcn_s_setprio(0);                                            \
  } while (0)

#define BAR        __builtin_amdgcn_s_barrier()
#define LGKM0      asm volatile("s_waitcnt lgkmcnt(0)" ::: "memory")
#define WAIT_VM(n) asm volatile("s_waitcnt vmcnt(" #n ")" ::: "memory")

  f32x4 acc[8][4];
#pragma unroll
  for (int i = 0; i < 8; ++i)
#pragma unroll
    for (int j = 0; j < 4; ++j) acc[i][j] = (f32x4)0.f;

  // --- prologue: tile0 fully, tile1 {B0,B1,A0}; A1(1) is issued at P1 of t=0.
  // 14 loads issued; vmcnt(6) -> first 8 (all of tile 0) landed.
  STG(Ag, sA, 0, 0, 0); STG(Ag, sA, 0, 1, 0);
  STG(Bg, sB, 0, 0, 0); STG(Bg, sB, 0, 1, 0);
  STG(Bg, sB, 1, 0, 1); STG(Bg, sB, 1, 1, 1);
  STG(Ag, sA, 1, 0, 1);
  WAIT_VM(6);
  BAR;

#pragma unroll 2
  for (int t = 0; t < NT; ++t) {
    const int buf  = t & 1;
    const int nbuf = buf ^ 1;

    // P1: quadrant (m0,n0)
    LDA(buf, 0); LDB(bf0, buf, 0);
    if (t + 1 < NT) STG(Ag, sA, nbuf, 1, t + 1);   // A1(t+1): nbuf A free since t-1's P3
    BAR; LGKM0;
    PH_MFMA(0, 0, bf0);
    BAR;

    // P2: quadrant (m0,n1)  (reuses af; loads bf1)
    LDB(bf1, buf, 1);
    BAR; LGKM0;
    PH_MFMA(0, 1, bf1);
    BAR;

    // P3: quadrant (m1,n1)  (reloads af; reuses bf1)
    LDA(buf, 1);
    if (t + 2 < NT) STG(Bg, sB, buf, 0, t + 2);    // B halves free after P2's barrier
    BAR; LGKM0;
    PH_MFMA(1, 1, bf1);
    BAR;

    // P4: quadrant (m1,n0)  (reuses af + bf0; no new ds reads)
    if (t + 2 < NT) { STG(Bg, sB, buf, 1, t + 2);  // B free after P2
                      STG(Ag, sA, buf, 0, t + 2); }// A halves free after P3's barrier
    BAR;
    PH_MFMA(1, 0, bf0);
    // boundary: ensure tile t+1 fully landed; keep 3 half-tiles (6 loads) in flight
    if      (t + 2 < NT) { WAIT_VM(6); }
    else if (t + 1 < NT) { WAIT_VM(0); }           // epilogue drain
    BAR;
  }

  // --- epilogue: C write (C/D map: col = lane&15, row = g*4 + reg)
  const int rowb = bm * 256 + wr * 128 + g * 4;
  const int colb = bn * 256 + wc * 64 + mm;
#pragma unroll
  for (int im = 0; im < 8; ++im) {
#pragma unroll
    for (int in2 = 0; in2 < 4; ++in2) {
      const int row = rowb + im * 16;
      const int col = colb + in2 * 16;
#pragma unroll
      for (int r = 0; r < 4; ++r)
        C[(size_t)(row + r) * N + col] = acc[im][in2][r];
    }
  }

#undef STG
#undef LDA
#undef LDB
#undef PH_MFMA
#undef BAR
#undef LGKM0
#undef WAIT_VM
}

// ---------------------------------------------------------------------------
extern "C" void kernel_launch(void* const* d_in, const int* in_sizes, int n_in,
                              void* d_out, int out_size, void* d_ws, size_t ws_size,
                              hipStream_t stream)
{
  const float* x   = (const float*)d_in[0];
  const int*   er0 = (const int*)d_in[1];
  const int*   ec0 = (const int*)d_in[2];
  const float* ev0 = (const float*)d_in[3];
  const int*   er1 = (const int*)d_in[4];
  const int*   ec1 = (const int*)d_in[5];
  const float* ev1 = (const float*)d_in[6];
  const int*   er2 = (const int*)d_in[7];
  const int*   ec2 = (const int*)d_in[8];
  const float* ev2 = (const float*)d_in[9];
  const int*   mr  = (const int*)d_in[10];
  const int*   mc  = (const int*)d_in[11];
  const float* mv  = (const float*)d_in[12];
  const int nnz_e0 = in_sizes[1];
  const int nnz_e1 = in_sizes[4];
  const int nnz_e2 = in_sizes[7];
  const int nnz_m  = in_sizes[10];

  int*   rp_all = (int*)d_ws;                              // 4*4096 ints
  int*   cc_all = rp_all + 4 * 4096;                       // 40960 ints used
  float* cv_all = (float*)(cc_all + 48 * 1024);            // 40960 floats used
  float* D      = (float*)(cv_all + 48 * 1024);            // [3*EROWS][F0] fp32 (12 MB)
  unsigned short* Mb = (unsigned short*)(D + (size_t)3 * EROWS * F0);  // 8 MB
  unsigned short* Ab = Mb + (size_t)NOUT * F0;             // 32 MB

  // 1) CSR-ize all four weights + cast x to bf16 (independent work, one node)
  hipLaunchKernelGGL(csr_cast_kernel, dim3(4 + 2048), dim3(256), 0, stream,
                     er0, ec0, ev0, nnz_e0,
                     er1, ec1, ev1, nnz_e1,
                     er2, ec2, ev2, nnz_e2,
                     mr,  mc,  mv,  nnz_m,
                     rp_all, cc_all, cv_all, x, Ab);

  // 2) expand chain (each launch depends on the previous -> stream order)
  hipLaunchKernelGGL((expand_csr_kernel<false>), dim3(EROWS), dim3(256), 0, stream,
                     rp_all + 0 * 4096, cc_all + 0 * 8192, cv_all + 0 * 8192,
                     D, (void*)D);
  hipLaunchKernelGGL((expand_csr_kernel<false>), dim3(EROWS), dim3(256), 0, stream,
                     rp_all + 1 * 4096, cc_all + 1 * 8192, cv_all + 1 * 8192,
                     D, (void*)(D + (size_t)EROWS * F0));
  hipLaunchKernelGGL((expand_csr_kernel<false>), dim3(EROWS), dim3(256), 0, stream,
                     rp_all + 2 * 4096, cc_all + 2 * 8192, cv_all + 2 * 8192,
                     D, (void*)(D + (size_t)2 * EROWS * F0));
  hipLaunchKernelGGL((expand_csr_kernel<true>), dim3(NOUT), dim3(256), 0, stream,
                     rp_all + 3 * 4096, cc_all + 3 * 8192, cv_all + 3 * 8192,
                     D, (void*)Mb);

  // 3) out = x @ M^T  (256^2 8-phase, 128 KiB dynamic LDS -> needs attribute)
  hipFuncSetAttribute(reinterpret_cast<const void*>(gemm256_kernel),
                      hipFuncAttributeMaxDynamicSharedMemorySize, 131072);
  hipLaunchKernelGGL(gemm256_kernel, dim3(NOUT / 256, MROWS / 256), dim3(512),
                     131072, stream, Ab, Mb, (float*)d_out);
}

// Round 4
// 237.277 us; speedup vs baseline: 1.1110x; 1.0125x over previous
//
#include <hip/hip_runtime.h>
#include <stdint.h>

#define F0    2048      // base input features (= GEMM K)
#define EROWS 512       // embed rows per level
#define NOUT  2048      // output features (= GEMM N)
#define MROWS 8192      // batch (= GEMM M)

typedef __attribute__((ext_vector_type(8))) short bf16x8;
typedef __attribute__((ext_vector_type(4))) float f32x4;
typedef __attribute__((ext_vector_type(8))) unsigned short u16x8;

typedef const __attribute__((address_space(1))) unsigned char ga_t;
typedef __attribute__((address_space(3))) unsigned char lds_t;

__device__ __forceinline__ void async_load16(const void* g, void* l) {
  __builtin_amdgcn_global_load_lds((ga_t*)g, (lds_t*)l, 16, 0, 0);
}

__device__ __forceinline__ unsigned short f2bf(float f) {
  unsigned int u = __builtin_bit_cast(unsigned int, f);
  u += 0x7fffu + ((u >> 16) & 1u);   // round-to-nearest-even
  return (unsigned short)(u >> 16);
}

// ---------------------------------------------------------------------------
// Blocks 0..3: CSR-ize weight b (grid=4; the x-cast rides in the expand
// launches so it overlaps the latency-bound expand chain).
// ---------------------------------------------------------------------------
__global__ __launch_bounds__(256) void csr_cast_kernel(
    const int* __restrict__ r0, const int* __restrict__ c0, const float* __restrict__ v0, int n0,
    const int* __restrict__ r1, const int* __restrict__ c1, const float* __restrict__ v1, int n1,
    const int* __restrict__ r2, const int* __restrict__ c2, const float* __restrict__ v2, int n2,
    const int* __restrict__ rm, const int* __restrict__ cm, const float* __restrict__ vm, int nm,
    int* __restrict__ rp_all, int* __restrict__ cc_all, float* __restrict__ cv_all)
{
  const int b = blockIdx.x;
  const int tid = threadIdx.x;

  // ---- CSR-ize one weight
  const int* rows; const int* cols; const float* vals; int nnz, nrows;
  if      (b == 0) { rows = r0; cols = c0; vals = v0; nnz = n0; nrows = EROWS; }
  else if (b == 1) { rows = r1; cols = c1; vals = v1; nnz = n1; nrows = EROWS; }
  else if (b == 2) { rows = r2; cols = c2; vals = v2; nnz = n2; nrows = EROWS; }
  else             { rows = rm; cols = cm; vals = vm; nnz = nm; nrows = NOUT; }
  int* rp  = rp_all + b * 4096;
  int* cc  = cc_all + b * 8192;          // main (b=3) spills into 16384 entries: region sized for it
  float* cv = cv_all + b * 8192;

  __shared__ int hist[NOUT + 1];
  __shared__ int tsum[256];

  for (int i = tid; i < nrows; i += 256) hist[i] = 0;
  __syncthreads();

  // --- histogram: 8 contiguous entries per thread per round
  int k0 = 0;
  for (; k0 + 2048 <= nnz; k0 += 2048) {
    const int kk = k0 + tid * 8;
    int4 ra = *(const int4*)(rows + kk);
    int4 rb = *(const int4*)(rows + kk + 4);
    atomicAdd(&hist[ra.x], 1); atomicAdd(&hist[ra.y], 1);
    atomicAdd(&hist[ra.z], 1); atomicAdd(&hist[ra.w], 1);
    atomicAdd(&hist[rb.x], 1); atomicAdd(&hist[rb.y], 1);
    atomicAdd(&hist[rb.z], 1); atomicAdd(&hist[rb.w], 1);
  }
  for (int k = k0 + tid; k < nnz; k += 256) atomicAdd(&hist[rows[k]], 1);
  __syncthreads();

  // --- exclusive scan: per-thread partials + parallel Hillis-Steele on 256
  const int per = nrows >> 8;            // 2 or 8
  const int base = tid * per;
  int sum = 0;
  for (int i = 0; i < per; ++i) sum += hist[base + i];
  tsum[tid] = sum;
  __syncthreads();
  for (int off = 1; off < 256; off <<= 1) {
    int add = (tid >= off) ? tsum[tid - off] : 0;
    __syncthreads();
    tsum[tid] += add;
    __syncthreads();
  }
  int run = (tid == 0) ? 0 : tsum[tid - 1];
  for (int i = 0; i < per; ++i) { int h = hist[base + i]; hist[base + i] = run; run += h; }
  __syncthreads();

  for (int i = tid; i < nrows; i += 256) rp[i] = hist[i];
  if (tid == 0) rp[nrows] = nnz;
  __syncthreads();

  // --- scatter: 8 contiguous entries per thread per round (hist = cursors)
  k0 = 0;
  for (; k0 + 2048 <= nnz; k0 += 2048) {
    const int kk = k0 + tid * 8;
    int4   ra = *(const int4*)(rows + kk);
    int4   rb = *(const int4*)(rows + kk + 4);
    int4   ca = *(const int4*)(cols + kk);
    int4   cb2 = *(const int4*)(cols + kk + 4);
    float4 va = *(const float4*)(vals + kk);
    float4 vb = *(const float4*)(vals + kk + 4);
    int p;
    p = atomicAdd(&hist[ra.x], 1); cc[p] = ca.x;  cv[p] = va.x;
    p = atomicAdd(&hist[ra.y], 1); cc[p] = ca.y;  cv[p] = va.y;
    p = atomicAdd(&hist[ra.z], 1); cc[p] = ca.z;  cv[p] = va.z;
    p = atomicAdd(&hist[ra.w], 1); cc[p] = ca.w;  cv[p] = va.w;
    p = atomicAdd(&hist[rb.x], 1); cc[p] = cb2.x; cv[p] = vb.x;
    p = atomicAdd(&hist[rb.y], 1); cc[p] = cb2.y; cv[p] = vb.y;
    p = atomicAdd(&hist[rb.z], 1); cc[p] = cb2.z; cv[p] = vb.z;
    p = atomicAdd(&hist[rb.w], 1); cc[p] = cb2.w; cv[p] = vb.w;
  }
  for (int k = k0 + tid; k < nnz; k += 256) {
    int p = atomicAdd(&hist[rows[k]], 1);
    cc[p] = cols[k]; cv[p] = vals[k];
  }
}

// ---------------------------------------------------------------------------
// Blocks [0, nrows): one block per dense output row (CSR expand).
// Blocks [nrows, nrows+512): x -> bf16 cast chunk (rides under the expand
// chain's latency; 512 cast blocks per launch, cast_base selects the chunk).
// ---------------------------------------------------------------------------
template <bool BF16OUT>
__global__ __launch_bounds__(256) void expand_csr_kernel(
    const int* __restrict__ rp, const int* __restrict__ cc,
    const float* __restrict__ cv, const float* __restrict__ Dsrc,
    void* __restrict__ out, int nrows,
    const float* __restrict__ x, unsigned short* __restrict__ Ab, int cast_base)
{
  const int b = blockIdx.x;
  const int tid = threadIdx.x;

  if (b >= nrows) {
    // ---- x cast: each block handles 1024 vec8
    const int cb = cast_base + (b - nrows);
    const float4* xp = (const float4*)x;
    u16x8* ap = (u16x8*)Ab;
#pragma unroll
    for (int it = 0; it < 4; ++it) {
      int i = cb * 1024 + it * 256 + tid;
      float4 a = xp[2 * i], c = xp[2 * i + 1];
      u16x8 o;
      o[0] = f2bf(a.x); o[1] = f2bf(a.y); o[2] = f2bf(a.z); o[3] = f2bf(a.w);
      o[4] = f2bf(c.x); o[5] = f2bf(c.y); o[6] = f2bf(c.z); o[7] = f2bf(c.w);
      ap[i] = o;
    }
    return;
  }

  const int r = b;
  __shared__ float acc[F0];
  __shared__ int   icol[128];
  __shared__ float ival[128];
  __shared__ int   icnt;

  float4* a4 = (float4*)acc;
  a4[tid * 2]     = (float4){0.f, 0.f, 0.f, 0.f};
  a4[tid * 2 + 1] = (float4){0.f, 0.f, 0.f, 0.f};
  if (tid == 0) icnt = 0;
  __syncthreads();

  const int s = rp[r], e = rp[r + 1];
  for (int i = s + tid; i < e; i += 256) {
    int c = cc[i]; float v = cv[i];
    if (c < F0) atomicAdd(&acc[c], v);
    else { int p = atomicAdd(&icnt, 1); if (p < 128) { icol[p] = c - F0; ival[p] = v; } }
  }
  __syncthreads();
  int n = icnt; if (n > 128) n = 128;

  float4 q0 = a4[tid * 2], q1 = a4[tid * 2 + 1];
  for (int j = 0; j < n; ++j) {
    const float4* src = (const float4*)(Dsrc + (size_t)icol[j] * F0) + tid * 2;
    float v = ival[j];
    float4 s0 = src[0], s1 = src[1];
    q0.x += v * s0.x; q0.y += v * s0.y; q0.z += v * s0.z; q0.w += v * s0.w;
    q1.x += v * s1.x; q1.y += v * s1.y; q1.z += v * s1.z; q1.w += v * s1.w;
  }

  if (BF16OUT) {
    u16x8 o;
    o[0] = f2bf(q0.x); o[1] = f2bf(q0.y); o[2] = f2bf(q0.z); o[3] = f2bf(q0.w);
    o[4] = f2bf(q1.x); o[5] = f2bf(q1.y); o[6] = f2bf(q1.z); o[7] = f2bf(q1.w);
    ((u16x8*)out)[(size_t)r * 256 + tid] = o;
  } else {
    float4* dst = (float4*)out + (size_t)r * 512 + tid * 2;
    dst[0] = q0; dst[1] = q1;
  }
}

// ---------------------------------------------------------------------------
// C[m,n] = sum_k A[m,k] * B[n,k]   (A: MROWSxK bf16, B: NOUTxK bf16, C fp32)
// 256x256 tile, BK=64, 512 threads = 8 waves (2M x 4N), per-wave 128x64 out.
//
// v4 = v3 + race fix. REGION USAGE IS WAVE-DEPENDENT: wr=1 waves read ONLY
// sA half 1 ("A1" region) for both qm; wc>=2 waves read ONLY sB half 1.
// Hence the P4b read cluster needs ALL FOUR half-tiles of t+1 forced, incl.
// A1(t+1) which was staged THIS tile (P1) and sat inside vm(8)'s allowance
// -> timing-dependent RAW race (v3 tripwire: passed once, diverged later).
// Fix: P4 vm(8)->vm(6) (forces A1(t+1); leaves {B0,B1,A0}(t+2) = 6 loads in
// flight), prologue vm(8)->vm(6) (forces A1(0)), tail vm(2)->vm(0).
//
// Schedule (reads ONE PHASE AHEAD so ds_read clusters overlap MFMA):
//   P1: STG A1(t+1); vm(8);      read bf1(t);            MFMA q00(afP,bf0)
//   P2: BAR;                     read afQ(t);            MFMA q01(afP,bf1)
//   P3: BAR; STG B0(t+2);                                MFMA q10(afQ,bf0)
//   P4: BAR; STG B1(t+2),A0(t+2); vm(6); BAR;
//                                read afP,bf0 (t+1);     MFMA q11(afQ,bf1)
// vmcnt proofs (in-order VMEM, 2 loads per STG):
//  - P4 vm(6) leaves {B0(t+2),B1(t+2),A0(t+2)} => A1(t+1) and all older
//    (A0/B0/B1(t+1)) done on every wave; BAR publishes -> P4b reads safe
//    for ALL waves (wr/wc half-1 readers included).
//  - afQ(t) regions (A0(t)/A1(t)) forced by t-1's P4 vm(6), published by
//    its BAR; P1's vm(8) is a no-op in steady state (6 in flight + 2 new).
// WAR safe: every ds_read's data is consumed by an MFMA before the wave
// enters the barrier that precedes the conflicting STG.
// ---------------------------------------------------------------------------
__global__ __launch_bounds__(512, 2) void gemm256_kernel(
    const unsigned short* __restrict__ A, const unsigned short* __restrict__ B,
    float* __restrict__ C)
{
  constexpr int K  = F0;        // 2048
  constexpr int N  = NOUT;      // 2048
  constexpr int NT = K / 64;    // 32 K-tiles

  extern __shared__ __align__(16) unsigned short lds[];
  unsigned short* sA = lds;           // [2 buf][2 half][128 rows][64] bf16 = 64 KiB
  unsigned short* sB = lds + 32768;   // same layout = 64 KiB

  const int tid  = threadIdx.x;
  const int lane = tid & 63;
  const int w    = tid >> 6;          // 0..7
  const int wr   = w >> 2;            // 0..1  (M half of the block tile)
  const int wc   = w & 3;             // 0..3  (N quarter)
  const int mm   = lane & 15;
  const int g    = lane >> 4;         // 0..3
  const int sx   = mm & 7;            // per-thread swizzle xor
  const int bm   = blockIdx.y;
  const int bn   = blockIdx.x;

  const unsigned short* Ag = A + (size_t)bm * 256 * K;
  const unsigned short* Bg = B + (size_t)bn * 256 * K;

  // staging: thread covers u0=tid (row r0) and u1=512+tid (row 64+r0);
  // LDS dest linear, global source pre-swizzled (both-sides involution).
  const int    r0    = tid >> 3;
  const int    c0    = (tid & 7) ^ (r0 & 7);
  const size_t goff0 = (size_t)r0 * K + c0 * 8;            // elems
  const size_t goff1 = goff0 + (size_t)64 * K;
  const int    loff0 = tid * 8;                            // elems in half region
  const int    loff1 = 4096 + tid * 8;

#define STG(Gb, Sb, buf, h, t) do {                                           \
    async_load16((Gb) + goff0 + (size_t)(h) * 128 * K + (t) * 64,             \
                 (Sb) + (buf) * 16384 + (h) * 8192 + loff0);                  \
    async_load16((Gb) + goff1 + (size_t)(h) * 128 * K + (t) * 64,             \
                 (Sb) + (buf) * 16384 + (h) * 8192 + loff1);                  \
  } while (0)

  // fragment read bases (swizzled slots; frag row & 7 == mm & 7)
  const unsigned short* paB = sA + (wr * 128 + mm) * 64;
  const unsigned short* pbB = sB + (wc * 64  + mm) * 64;
  const int s0 = ((0 * 4 + g) ^ sx) * 8;   // ks=0 slot offset (elems)
  const int s1 = ((1 * 4 + g) ^ sx) * 8;   // ks=1

  bf16x8 afP[4][2];     // A quadrant qm=0 rows (per-wave: wr half, lower 64)
  bf16x8 afQ[4][2];     // A quadrant qm=1 rows (upper 64 of the wr half)
  bf16x8 bf0[2][2];     // B quadrant qn=0 (per-wave: wc quarter, lower 32)
  bf16x8 bf1[2][2];     // B quadrant qn=1

#define LDA(dst, buf, qm) do {                                                \
    const unsigned short* p_ = paB + (buf) * 16384 + (qm) * 4096;             \
    _Pragma("unroll") for (int tm = 0; tm < 4; ++tm) {                        \
      dst[tm][0] = *(const bf16x8*)(p_ + tm * 1024 + s0);                     \
      dst[tm][1] = *(const bf16x8*)(p_ + tm * 1024 + s1);                     \
    } } while (0)

#define LDB(dst, buf, qn) do {                                                \
    const unsigned short* p_ = pbB + (buf) * 16384 + (qn) * 2048;             \
    _Pragma("unroll") for (int tn = 0; tn < 2; ++tn) {                        \
      dst[tn][0] = *(const bf16x8*)(p_ + tn * 1024 + s0);                     \
      dst[tn][1] = *(const bf16x8*)(p_ + tn * 1024 + s1);                     \
    } } while (0)

#define MFMA_Q(qm, qn, afX, bfX) do {                                         \
    __builtin_amdgcn_s_setprio(1);                                            \
    _Pragma("unroll") for (int tm = 0; tm < 4; ++tm)                          \
    _Pragma("unroll") for (int tn = 0; tn < 2; ++tn) {                        \
      acc[(qm)*4+tm][(qn)*2+tn] = __builtin_amdgcn_mfma_f32_16x16x32_bf16(    \
          afX[tm][0], bfX[tn][0], acc[(qm)*4+tm][(qn)*2+tn], 0, 0, 0);        \
      acc[(qm)*4+tm][(qn)*2+tn] = __builtin_amdgcn_mfma_f32_16x16x32_bf16(    \
          afX[tm][1], bfX[tn][1], acc[(qm)*4+tm][(qn)*2+tn], 0, 0, 0);        \
    }                                                                         \
    __builtin_amdgcn_s_setprio(0);                                            \
  } while (0)

#define CFENCE     asm volatile("" ::: "memory")
#define BAR        do { CFENCE; __builtin_amdgcn_s_barrier(); CFENCE; } while (0)
#define SCHED0     __builtin_amdgcn_sched_barrier(0)
#define WAIT_VM(n) asm volatile("s_waitcnt vmcnt(" #n ")" ::: "memory")

  f32x4 acc[8][4];
#pragma unroll
  for (int i = 0; i < 8; ++i)
#pragma unroll
    for (int j = 0; j < 4; ++j) acc[i][j] = (f32x4)0.f;

  // --- prologue: mimic steady-state issue order so vmcnt counts line up.
  STG(Bg, sB, 0, 0, 0);            // B0(0)
  STG(Bg, sB, 0, 1, 0);            // B1(0)
  STG(Ag, sA, 0, 0, 0);            // A0(0)
  STG(Ag, sA, 0, 1, 0);            // A1(0)
  STG(Bg, sB, 1, 0, 1);            // B0(1)
  STG(Bg, sB, 1, 1, 1);            // B1(1)
  STG(Ag, sA, 1, 0, 1);            // A0(1)
  WAIT_VM(6);                      // forces B0,B1,A0,A1(0) on THIS wave
  BAR;                             // publication rendezvous: all of tile 0
                                   // landed block-wide before any ds_read
                                   // (incl. A1(0) for wr=1 waves).
  SCHED0;
  LDA(afP, 0, 0);
  LDB(bf0, 0, 0);

#pragma unroll 2
  for (int t = 0; t < NT; ++t) {
    const int buf  = t & 1;
    const int nbuf = buf ^ 1;

    // ---- P1 (no barrier: safety anchored at prev tile's P4 {vm;BAR} /
    //      prologue BAR for t=0)
    if (t + 1 < NT) STG(Ag, sA, nbuf, 1, t + 1);   // A1(t+1)
    if (t + 1 < NT) { WAIT_VM(8); } else { WAIT_VM(0); }
    SCHED0;
    LDB(bf1, buf, 1);                              // overlaps q00
    MFMA_Q(0, 0, afP, bf0);

    // ---- P2
    BAR; SCHED0;
    LDA(afQ, buf, 1);                              // overlaps q01
    MFMA_Q(0, 1, afP, bf1);

    // ---- P3
    BAR;
    if (t + 2 < NT) STG(Bg, sB, buf, 0, t + 2);    // B0(t+2): readers done (P2 BAR)
    MFMA_Q(1, 0, afQ, bf0);

    // ---- P4
    BAR;
    if (t + 2 < NT) {
      STG(Bg, sB, buf, 1, t + 2);                  // B1(t+2): free since P3 BAR
      STG(Ag, sA, buf, 0, t + 2);                  // A0(t+2): free since P3 BAR
      WAIT_VM(6);                                  // ALL of tile t+1 landed
      BAR; SCHED0;                                 // publish to all waves
      LDA(afP, nbuf, 0);                           // overlaps q11
      LDB(bf0, nbuf, 0);
    } else if (t + 1 < NT) {
      WAIT_VM(0);                                  // tail: force A1(NT-1) too
      BAR; SCHED0;
      LDA(afP, nbuf, 0);
      LDB(bf0, nbuf, 0);
    }
    MFMA_Q(1, 1, afQ, bf1);
  }

  // --- epilogue: C write (C/D map: col = lane&15, row = g*4 + reg)
  const int rowb = bm * 256 + wr * 128 + g * 4;
  const int colb = bn * 256 + wc * 64 + mm;
#pragma unroll
  for (int im = 0; im < 8; ++im) {
#pragma unroll
    for (int in2 = 0; in2 < 4; ++in2) {
      const int row = rowb + im * 16;
      const int col = colb + in2 * 16;
#pragma unroll
      for (int r = 0; r < 4; ++r)
        C[(size_t)(row + r) * N + col] = acc[im][in2][r];
    }
  }

#undef STG
#undef LDA
#undef LDB
#undef MFMA_Q
#undef CFENCE
#undef BAR
#undef SCHED0
#undef WAIT_VM
}

// ---------------------------------------------------------------------------
extern "C" void kernel_launch(void* const* d_in, const int* in_sizes, int n_in,
                              void* d_out, int out_size, void* d_ws, size_t ws_size,
                              hipStream_t stream)
{
  const float* x   = (const float*)d_in[0];
  const int*   er0 = (const int*)d_in[1];
  const int*   ec0 = (const int*)d_in[2];
  const float* ev0 = (const float*)d_in[3];
  const int*   er1 = (const int*)d_in[4];
  const int*   ec1 = (const int*)d_in[5];
  const float* ev1 = (const float*)d_in[6];
  const int*   er2 = (const int*)d_in[7];
  const int*   ec2 = (const int*)d_in[8];
  const float* ev2 = (const float*)d_in[9];
  const int*   mr  = (const int*)d_in[10];
  const int*   mc  = (const int*)d_in[11];
  const float* mv  = (const float*)d_in[12];
  const int nnz_e0 = in_sizes[1];
  const int nnz_e1 = in_sizes[4];
  const int nnz_e2 = in_sizes[7];
  const int nnz_m  = in_sizes[10];

  int*   rp_all = (int*)d_ws;                              // 4*4096 ints
  int*   cc_all = rp_all + 4 * 4096;                       // 40960 ints used
  float* cv_all = (float*)(cc_all + 48 * 1024);            // 40960 floats used
  float* D      = (float*)(cv_all + 48 * 1024);            // [3*EROWS][F0] fp32 (12 MB)
  unsigned short* Mb = (unsigned short*)(D + (size_t)3 * EROWS * F0);  // 8 MB
  unsigned short* Ab = Mb + (size_t)NOUT * F0;             // 32 MB

  // 1) CSR-ize all four weights (4 blocks; x-cast moved into expand launches)
  hipLaunchKernelGGL(csr_cast_kernel, dim3(4), dim3(256), 0, stream,
                     er0, ec0, ev0, nnz_e0,
                     er1, ec1, ev1, nnz_e1,
                     er2, ec2, ev2, nnz_e2,
                     mr,  mc,  mv,  nnz_m,
                     rp_all, cc_all, cv_all);

  // 2) expand chain; each launch carries 512 x-cast blocks (2048 total)
  hipLaunchKernelGGL((expand_csr_kernel<false>), dim3(EROWS + 512), dim3(256), 0, stream,
                     rp_all + 0 * 4096, cc_all + 0 * 8192, cv_all + 0 * 8192,
                     D, (void*)D, EROWS, x, Ab, 0);
  hipLaunchKernelGGL((expand_csr_kernel<false>), dim3(EROWS + 512), dim3(256), 0, stream,
                     rp_all + 1 * 4096, cc_all + 1 * 8192, cv_all + 1 * 8192,
                     D, (void*)(D + (size_t)EROWS * F0), EROWS, x, Ab, 512);
  hipLaunchKernelGGL((expand_csr_kernel<false>), dim3(EROWS + 512), dim3(256), 0, stream,
                     rp_all + 2 * 4096, cc_all + 2 * 8192, cv_all + 2 * 8192,
                     D, (void*)(D + (size_t)2 * EROWS * F0), EROWS, x, Ab, 1024);
  hipLaunchKernelGGL((expand_csr_kernel<true>), dim3(NOUT + 512), dim3(256), 0, stream,
                     rp_all + 3 * 4096, cc_all + 3 * 8192, cv_all + 3 * 8192,
                     D, (void*)Mb, NOUT, x, Ab, 1536);

  // 3) out = x @ M^T  (256^2, read-ahead overlap schedule, 128 KiB dyn LDS)
  hipFuncSetAttribute(reinterpret_cast<const void*>(gemm256_kernel),
                      hipFuncAttributeMaxDynamicSharedMemorySize, 131072);
  hipLaunchKernelGGL(gemm256_kernel, dim3(NOUT / 256, MROWS / 256), dim3(512),
                     131072, stream, Ab, Mb, (float*)d_out);
}